// Round 10
// baseline (34.159 us; speedup 1.0000x reference)
//
#include <hip/hip_runtime.h>

// Denoiser MLP (2->16, 5x 16->16, 16->2), fp32 in/out, via v_mfma_f32_32x32x16_f16.
// R10: latency-hiding product. R8 (launch_bounds 4/SIMD) was the only recent
// win (-15%); R8==R9 killed the pin/AGPR theories. Diagnosis: latency-bound
// (VALUBusy 53% + MfmaUtil 26%, both low, occupancy 28%). Fix: raise
// (waves/SIMD x streams/wave): 4 independent 32-pt streams per wave
// (128 pts/iter, 2 packed bins feed 4 streams via hi-masked wi0/wi1) and
// __launch_bounds__(256,3) => 12 independent MFMA chains per SIMD.
//
// Mapping (verified R6-R9, absmax 7.8e-3):
//   A (32x16) = [W; W], B (16x32) = 32 points' features (transposed)
//   A frag: lane l holds A[i=l&31][k=8*(l>>5)+j]
//   B frag: lane l holds B[k=8*(l>>5)+j][n=l&31]
//   D frag: lane l holds D[i=(reg&3)+8*(reg>>2)+4*(l>>5)][n=l&31]
// D regs 0-7 at hi=l>>5 = rows {0-3,8-11}/{4-7,12-15}; next-layer weights
// column-permuted [0-3,8-11 | 4-7,12-15] -> layers chain in register order,
// zero cross-lane traffic.
// Input trick: bin = pack4(cvtpk(x,y),0,0,0) puts lane's own point at
// k=8*hi+{0,1}; wi0 (W at k0,1) picks hi=0 lanes' points (stream base+0..31),
// wi1 (W at k8,9) picks hi=1 lanes' (base+32..63). Second bin from
// x[base+64+lane] gives streams 2,3 the same way.

typedef _Float16 h8 __attribute__((ext_vector_type(8)));
typedef float f16v __attribute__((ext_vector_type(16)));
typedef float f4 __attribute__((ext_vector_type(4)));
typedef float f2 __attribute__((ext_vector_type(2)));
typedef unsigned int u32;
typedef u32 u4v __attribute__((ext_vector_type(4)));

static __device__ __forceinline__ f16v mfma32(h8 a, h8 b, f16v c) {
    return __builtin_amdgcn_mfma_f32_32x32x16_f16(a, b, c, 0, 0, 0);
}

static __device__ __forceinline__ u32 cvtpk(float a, float b) {
    return __builtin_bit_cast(u32, __builtin_amdgcn_cvt_pkrtz(a, b));
}

static __device__ __forceinline__ h8 pack4(u32 a, u32 b, u32 c, u32 d) {
    u4v p = {a, b, c, d};
    return __builtin_bit_cast(h8, p);
}

// quad-permuted weight fragment: j0-3 = cols 4*hi.., j4-7 = cols 8+4*hi..
static __device__ __forceinline__ h8 wfrag(const float* row, int hi) {
    const f4* r4 = (const f4*)row;
    f4 q0 = r4[hi], q1 = r4[hi + 2];
    return pack4(cvtpk(q0.x, q0.y), cvtpk(q0.z, q0.w),
                 cvtpk(q1.x, q1.y), cvtpk(q1.z, q1.w));
}

// relu + cvt of D regs 0-7 -> next layer's B fragment (order-preserving)
static __device__ __forceinline__ h8 cvt_relu8(f16v a) {
    h8 hb = pack4(cvtpk(a[0], a[1]), cvtpk(a[2], a[3]),
                  cvtpk(a[4], a[5]), cvtpk(a[6], a[7]));
    const h8 z = {};
    return __builtin_elementwise_max(hb, z);   // 4x v_pk_max_f16
}

__global__ __launch_bounds__(256, 3) void denoiser_mfma32(
    const f2* __restrict__ x,        // [N] points (x0,x1)
    const float* __restrict__ w_in,  // [16][2]
    const float* __restrict__ w_mid, // [5][16][16]
    const float* __restrict__ w_out, // [2][16]
    f2* __restrict__ out,            // [N] (o0,o1)
    int n)
{
    const int lane = threadIdx.x & 63;
    const int m    = lane & 15;   // weight row (rows duplicated mod 16)
    const int hi   = lane >> 5;   // half-wave / k-group
    const int wave = threadIdx.x >> 6;

    const h8 hz = {};

    // ---- one-time weight fragments ----
    u32 wxy = cvtpk(w_in[2 * m], w_in[2 * m + 1]);
    h8 wi0 = hi == 0 ? pack4(wxy, 0u, 0u, 0u) : hz;   // picks pts 0..31 of a bin
    h8 wi1 = hi == 1 ? pack4(wxy, 0u, 0u, 0u) : hz;   // picks pts 32..63

    h8 wm0 = wfrag(w_mid + 0 * 256 + m * 16, hi);
    h8 wm1 = wfrag(w_mid + 1 * 256 + m * 16, hi);
    h8 wm2 = wfrag(w_mid + 2 * 256 + m * 16, hi);
    h8 wm3 = wfrag(w_mid + 3 * 256 + m * 16, hi);
    h8 wm4 = wfrag(w_mid + 4 * 256 + m * 16, hi);

    h8 wo = m < 2 ? wfrag(w_out + m * 16, hi) : hz;

    // single one-time pin: zero C-operand stays resident, un-rematerializable
    f16v z16 = {};
    asm("" : "+v"(z16));

    const int nchunks = (n + 511) >> 9;     // 512 pts per block-iteration
    for (int c = blockIdx.x; c < nchunks; c += gridDim.x) {
        const int base = c * 512 + wave * 128;   // this wave's 128 points
        const bool full = (base + 128 <= n);     // wave-uniform

        f2 xyA, xyB;
        if (full) {
            xyA = x[base + lane];
            xyB = x[base + 64 + lane];
        } else {
            int pA = base + lane, pB = base + 64 + lane;
            xyA = x[pA < n ? pA : n - 1];
            xyB = x[pB < n ? pB : n - 1];
        }

        // ---- input layer: 2 bins -> 4 streams ----
        h8 binA = pack4(cvtpk(xyA.x, xyA.y), 0u, 0u, 0u);
        h8 binB = pack4(cvtpk(xyB.x, xyB.y), 0u, 0u, 0u);
        f16v a0 = mfma32(wi0, binA, z16);    // pts base+  0..31
        f16v a1 = mfma32(wi1, binA, z16);    // pts base+ 32..63
        f16v a2 = mfma32(wi0, binB, z16);    // pts base+ 64..95
        f16v a3 = mfma32(wi1, binB, z16);    // pts base+ 96..127
        h8 b0 = cvt_relu8(a0);
        h8 b1 = cvt_relu8(a1);
        h8 b2 = cvt_relu8(a2);
        h8 b3 = cvt_relu8(a3);

        // ---- 5 mid layers: 4 independent streams (ILP) ----
        a0 = mfma32(wm0, b0, z16);  a1 = mfma32(wm0, b1, z16);
        a2 = mfma32(wm0, b2, z16);  a3 = mfma32(wm0, b3, z16);
        b0 = cvt_relu8(a0);  b1 = cvt_relu8(a1);
        b2 = cvt_relu8(a2);  b3 = cvt_relu8(a3);

        a0 = mfma32(wm1, b0, z16);  a1 = mfma32(wm1, b1, z16);
        a2 = mfma32(wm1, b2, z16);  a3 = mfma32(wm1, b3, z16);
        b0 = cvt_relu8(a0);  b1 = cvt_relu8(a1);
        b2 = cvt_relu8(a2);  b3 = cvt_relu8(a3);

        a0 = mfma32(wm2, b0, z16);  a1 = mfma32(wm2, b1, z16);
        a2 = mfma32(wm2, b2, z16);  a3 = mfma32(wm2, b3, z16);
        b0 = cvt_relu8(a0);  b1 = cvt_relu8(a1);
        b2 = cvt_relu8(a2);  b3 = cvt_relu8(a3);

        a0 = mfma32(wm3, b0, z16);  a1 = mfma32(wm3, b1, z16);
        a2 = mfma32(wm3, b2, z16);  a3 = mfma32(wm3, b3, z16);
        b0 = cvt_relu8(a0);  b1 = cvt_relu8(a1);
        b2 = cvt_relu8(a2);  b3 = cvt_relu8(a3);

        a0 = mfma32(wm4, b0, z16);  a1 = mfma32(wm4, b1, z16);
        a2 = mfma32(wm4, b2, z16);  a3 = mfma32(wm4, b3, z16);
        b0 = cvt_relu8(a0);  b1 = cvt_relu8(a1);
        b2 = cvt_relu8(a2);  b3 = cvt_relu8(a3);

        // ---- output layer: rows 0,1 -> regs 0,1 @ hi=0 ----
        a0 = mfma32(wo, b0, z16);
        a1 = mfma32(wo, b1, z16);
        a2 = mfma32(wo, b2, z16);
        a3 = mfma32(wo, b3, z16);

        if (lane < 32) {
            int p0 = base + lane;
            if (full) {
                out[p0]      = (f2){a0[0], a0[1]};
                out[p0 + 32] = (f2){a1[0], a1[1]};
                out[p0 + 64] = (f2){a2[0], a2[1]};
                out[p0 + 96] = (f2){a3[0], a3[1]};
            } else {
                if (p0 < n)      out[p0]      = (f2){a0[0], a0[1]};
                if (p0 + 32 < n) out[p0 + 32] = (f2){a1[0], a1[1]};
                if (p0 + 64 < n) out[p0 + 64] = (f2){a2[0], a2[1]};
                if (p0 + 96 < n) out[p0 + 96] = (f2){a3[0], a3[1]};
            }
        }
    }
}

extern "C" void kernel_launch(void* const* d_in, const int* in_sizes, int n_in,
                              void* d_out, int out_size, void* d_ws, size_t ws_size,
                              hipStream_t stream) {
    const float* x     = (const float*)d_in[0];
    const float* w_in  = (const float*)d_in[1];
    const float* w_mid = (const float*)d_in[2];
    const float* w_out = (const float*)d_in[3];

    int n = in_sizes[0] / 2;          // number of points
    int nchunks = (n + 511) / 512;
    int blocks = nchunks < 2048 ? nchunks : 2048;  // persistent

    denoiser_mfma32<<<blocks, 256, 0, stream>>>(
        (const f2*)x, w_in, w_mid, w_out, (f2*)d_out, n);
}

// Round 11
// 32.804 us; speedup vs baseline: 1.0413x; 1.0413x over previous
//
#include <hip/hip_runtime.h>

// Denoiser MLP (2->16, 5x 16->16, 16->2), fp32 in/out, via v_mfma_f32_32x32x16_f16.
// R11: Little's-law fix. R4-R10 plateau ~33-38us across wildly different
// compute structures; per-SIMD VALU ~14%, MFMA ~7% (CU-level counters /4);
// effective read BW ~1.3 TB/s == (1 outstanding 512B load/wave) / ~900ns HBM
// latency (L3 flushed between replays by the harness's 268MB fills). The
// kernel is read-LATENCY-bound, not compute-bound. Fix: depth-2 software
// pipeline over the grid-stride loop -- each wave keeps 16B/lane (2 chunks)
// of x in flight during the entire compute body; x4 waves/SIMD => ~4KB/SIMD
// in flight => ~4.4 TB/s ceiling, read floor ~8us.
//
// Mapping (verified R6-R10, absmax 7.8e-3):
//   A (32x16) = [W; W], B (16x32) = 32 points' features (transposed)
//   A frag: lane l holds A[i=l&31][k=8*(l>>5)+j]
//   B frag: lane l holds B[k=8*(l>>5)+j][n=l&31]
//   D frag: lane l holds D[i=(reg&3)+8*(reg>>2)+4*(l>>5)][n=l&31]
// D regs 0-7 at hi=l>>5 = rows {0-3,8-11}/{4-7,12-15}; next-layer weights
// column-permuted [0-3,8-11 | 4-7,12-15] -> layers chain in register order.
// Input trick: bin = pack4(cvtpk(x,y),0,0,0); wi0 (W at k0,1) computes hi=0
// lanes' points (stream0 = pts base+0..31), wi1 (W at k8,9) hi=1 lanes'
// (stream1 = pts base+32..63).

typedef _Float16 h8 __attribute__((ext_vector_type(8)));
typedef float f16v __attribute__((ext_vector_type(16)));
typedef float f4 __attribute__((ext_vector_type(4)));
typedef float f2 __attribute__((ext_vector_type(2)));
typedef unsigned int u32;
typedef u32 u4v __attribute__((ext_vector_type(4)));

static __device__ __forceinline__ f16v mfma32(h8 a, h8 b, f16v c) {
    return __builtin_amdgcn_mfma_f32_32x32x16_f16(a, b, c, 0, 0, 0);
}

static __device__ __forceinline__ u32 cvtpk(float a, float b) {
    return __builtin_bit_cast(u32, __builtin_amdgcn_cvt_pkrtz(a, b));
}

static __device__ __forceinline__ h8 pack4(u32 a, u32 b, u32 c, u32 d) {
    u4v p = {a, b, c, d};
    return __builtin_bit_cast(h8, p);
}

// quad-permuted weight fragment: j0-3 = cols 4*hi.., j4-7 = cols 8+4*hi..
static __device__ __forceinline__ h8 wfrag(const float* row, int hi) {
    const f4* r4 = (const f4*)row;
    f4 q0 = r4[hi], q1 = r4[hi + 2];
    return pack4(cvtpk(q0.x, q0.y), cvtpk(q0.z, q0.w),
                 cvtpk(q1.x, q1.y), cvtpk(q1.z, q1.w));
}

// relu + cvt of D regs 0-7 -> next layer's B fragment (order-preserving)
static __device__ __forceinline__ h8 cvt_relu8(f16v a) {
    h8 hb = pack4(cvtpk(a[0], a[1]), cvtpk(a[2], a[3]),
                  cvtpk(a[4], a[5]), cvtpk(a[6], a[7]));
    const h8 z = {};
    return __builtin_elementwise_max(hb, z);   // 4x v_pk_max_f16
}

__global__ __launch_bounds__(256, 4) void denoiser_mfma32(
    const f2* __restrict__ x,        // [N] points (x0,x1)
    const float* __restrict__ w_in,  // [16][2]
    const float* __restrict__ w_mid, // [5][16][16]
    const float* __restrict__ w_out, // [2][16]
    f2* __restrict__ out,            // [N] (o0,o1)
    int n)
{
    const int lane = threadIdx.x & 63;
    const int m    = lane & 15;   // weight row (rows duplicated mod 16)
    const int hi   = lane >> 5;   // half-wave / k-group
    const int wave = threadIdx.x >> 6;

    const h8 hz = {};

    // ---- one-time weight fragments ----
    u32 wxy = cvtpk(w_in[2 * m], w_in[2 * m + 1]);
    h8 wi0 = hi == 0 ? pack4(wxy, 0u, 0u, 0u) : hz;   // stream0: pts 0..31
    h8 wi1 = hi == 1 ? pack4(wxy, 0u, 0u, 0u) : hz;   // stream1: pts 32..63

    h8 wm0 = wfrag(w_mid + 0 * 256 + m * 16, hi);
    h8 wm1 = wfrag(w_mid + 1 * 256 + m * 16, hi);
    h8 wm2 = wfrag(w_mid + 2 * 256 + m * 16, hi);
    h8 wm3 = wfrag(w_mid + 3 * 256 + m * 16, hi);
    h8 wm4 = wfrag(w_mid + 4 * 256 + m * 16, hi);

    h8 wo = m < 2 ? wfrag(w_out + m * 16, hi) : hz;

    // one-time pin: zero C-operand stays resident, un-rematerializable
    f16v z16 = {};
    asm("" : "+v"(z16));

    const int nchunks = (n + 255) >> 8;     // 256-pt block chunks
    const int stride  = gridDim.x;
    const int nm1     = n - 1;

    // clamped chunk load: this wave's 64 points of chunk c
    auto loadx = [&](int c) -> f2 {
        int pi = c * 256 + wave * 64 + lane;
        return x[pi < n ? pi : nm1];
    };

    // full MLP + store for chunk c with preloaded xy
    auto body = [&](int c, f2 xy) {
        const int base = c * 256 + wave * 64;
        h8 bin = pack4(cvtpk(xy.x, xy.y), 0u, 0u, 0u);
        f16v a0 = mfma32(wi0, bin, z16);
        f16v a1 = mfma32(wi1, bin, z16);
        h8 b0 = cvt_relu8(a0);
        h8 b1 = cvt_relu8(a1);

        a0 = mfma32(wm0, b0, z16);  a1 = mfma32(wm0, b1, z16);
        b0 = cvt_relu8(a0);         b1 = cvt_relu8(a1);
        a0 = mfma32(wm1, b0, z16);  a1 = mfma32(wm1, b1, z16);
        b0 = cvt_relu8(a0);         b1 = cvt_relu8(a1);
        a0 = mfma32(wm2, b0, z16);  a1 = mfma32(wm2, b1, z16);
        b0 = cvt_relu8(a0);         b1 = cvt_relu8(a1);
        a0 = mfma32(wm3, b0, z16);  a1 = mfma32(wm3, b1, z16);
        b0 = cvt_relu8(a0);         b1 = cvt_relu8(a1);
        a0 = mfma32(wm4, b0, z16);  a1 = mfma32(wm4, b1, z16);
        b0 = cvt_relu8(a0);         b1 = cvt_relu8(a1);

        a0 = mfma32(wo, b0, z16);
        a1 = mfma32(wo, b1, z16);

        if (lane < 32) {
            int p0 = base + lane;
            if (base + 64 <= n) {
                out[p0]      = (f2){a0[0], a0[1]};
                out[p0 + 32] = (f2){a1[0], a1[1]};
            } else {
                if (p0 < n)      out[p0]      = (f2){a0[0], a0[1]};
                if (p0 + 32 < n) out[p0 + 32] = (f2){a1[0], a1[1]};
            }
        }
    };

    // ---- depth-2 software pipeline over the grid-stride loop ----
    int c = blockIdx.x;
    f2 xyA = loadx(c);                       // chunk c
    f2 xyB = loadx(c + stride < nchunks ? c + stride : c);  // chunk c+s

    for (; c < nchunks; c += 2 * stride) {
        const int cB  = c + stride;
        const int cA2 = c + 2 * stride;
        const int cB2 = c + 3 * stride;

        // issue next pair's loads FIRST -> 16B/lane in flight during compute
        f2 xyA2 = loadx(cA2 < nchunks ? cA2 : c);
        f2 xyB2 = loadx(cB2 < nchunks ? cB2 : c);

        body(c, xyA);
        if (cB < nchunks) body(cB, xyB);

        xyA = xyA2;
        xyB = xyB2;
    }
}

extern "C" void kernel_launch(void* const* d_in, const int* in_sizes, int n_in,
                              void* d_out, int out_size, void* d_ws, size_t ws_size,
                              hipStream_t stream) {
    const float* x     = (const float*)d_in[0];
    const float* w_in  = (const float*)d_in[1];
    const float* w_mid = (const float*)d_in[2];
    const float* w_out = (const float*)d_in[3];

    int n = in_sizes[0] / 2;          // number of points
    int nchunks = (n + 255) / 256;
    int blocks = nchunks < 2048 ? nchunks : 2048;  // persistent

    denoiser_mfma32<<<blocks, 256, 0, stream>>>(
        (const f2*)x, w_in, w_mid, w_out, (f2*)d_out, n);
}